// Round 2
// baseline (77.780 us; speedup 1.0000x reference)
//
#include <hip/hip_runtime.h>

// NeRFDecoderHead: ray-marched occupancy render. ALL I/O is float32.
//   inputs: rays_o (R,3), rays_d (R,3), voxel (1,200,200,16), rgb_recon (3,200,200,16)
//   output: depth (R) ++ rgb_marched (R,3), flat float32.
//
// v3: predicated chunked march (latency-chain fix). v2 proved the loop is NOT
// gather-bound (4x fewer loads, zero delta): it is bound by the serial
// per-sample dependency  loads -> sigmoid -> c -> break, i.e. one memory
// round-trip PER SAMPLE, times the wave-max sample count. v3 removes the
// per-sample break:
//   * p = min(c+sig,1) - min(c,1) is exactly 0 once saturated (c>=1), and
//     sig:=0 for outside/padded samples makes p exactly 0 there as well ->
//     contributions self-mask, no control dependency inside a chunk.
//   * samples processed in fully-unrolled chunks of 4; all 4 samples' loads
//     are issueable up front -> ~1 latency round per 4 samples.
//   * break between chunks on a wave-uniform __all(done) ballot (also removes
//     per-lane divergence; wave runs to its max-lane anyway).
//   * exited rays (prefix property: origin inside convex bbox => once outside,
//     always outside; c frozen after exit) get the forced-last-sample term
//     once at the end: depth += (1-c)*z_last.
// Pack kernel from v2 dropped (pure +3.4us cost, no march benefit).

namespace {
constexpr int DX = 200, DY = 200, DZ = 16;
constexpr int GRID_N = DX * DY * DZ;   // 640000 per channel
constexpr int NS = 287;                // N_SAMPLES
constexpr float ZSTEP = 0.2f;          // stepsize(0.5) * voxel_size(0.4)
constexpr int CH = 4;                  // chunk size (latency-hiding depth)
} // namespace

extern "C" __global__ void __launch_bounds__(256)
nerf_march_kernel(const float* __restrict__ ro,
                  const float* __restrict__ rd,
                  const float* __restrict__ vox,
                  const float* __restrict__ rgbg,
                  float* __restrict__ out, int R)
{
    const int r = blockIdx.x * blockDim.x + threadIdx.x;
    if (r >= R) return;

    const float ox = ro[3 * r + 0];
    const float oy = ro[3 * r + 1];
    const float oz = ro[3 * r + 2];
    const float dx = rd[3 * r + 0];
    const float dy = rd[3 * r + 1];
    const float dz = rd[3 * r + 2];

    float c = 0.0f;                 // running (unclamped) cumsum of probs_raw
    float depth = 0.0f;
    float a0 = 0.0f, a1 = 0.0f, a2 = 0.0f;
    bool  exited = false;           // some real sample fell outside the bbox
    const float zlast = ZSTEP * (float)(NS - 1);   // 57.2

    #pragma unroll 1
    for (int n0 = 0; n0 < NS; n0 += CH) {
        #pragma unroll
        for (int j = 0; j < CH; ++j) {
            const int   n = n0 + j;
            const float z = ZSTEP * (float)n;
            const float px = fmaf(dx, z, ox);
            const float py = fmaf(dy, z, oy);
            const float pz = fmaf(dz, z, oz);

            const bool real   = (n < NS);          // NS not divisible by CH
            const bool in_box = (px >= -40.0f) & (px <= 40.0f) &
                                (py >= -40.0f) & (py <= 40.0f) &
                                (pz >= -1.0f)  & (pz <= 5.4f);
            const bool valid  = real & in_box;
            exited |= (real & !in_box);

            // trilinear index/weights (align_corners=true: idx = u*(dim-1));
            // clamped, so loads are safe even for invalid samples.
            const float fx = fminf(fmaxf(fmaf(px, 2.4875f,  99.5f),    0.0f), 199.0f);
            const float fy = fminf(fmaxf(fmaf(py, 2.4875f,  99.5f),    0.0f), 199.0f);
            const float fz = fminf(fmaxf(fmaf(pz, 2.34375f, 2.34375f), 0.0f), 15.0f);
            const int ix = min((int)fx, DX - 2);   // fx >= 0 so cast == floor
            const int iy = min((int)fy, DY - 2);
            const int iz = min((int)fz, DZ - 2);
            const float wx = fx - (float)ix, wy = fy - (float)iy, wz = fz - (float)iz;
            const float ux = 1.0f - wx, uy = 1.0f - wy, uz = 1.0f - wz;

            const float w000 = ux * uy * uz, w001 = ux * uy * wz;
            const float w010 = ux * wy * uz, w011 = ux * wy * wz;
            const float w100 = wx * uy * uz, w101 = wx * uy * wz;
            const float w110 = wx * wy * uz, w111 = wx * wy * wz;

            const int base = (ix * DY + iy) * DZ + iz;
            constexpr int SX = DY * DZ;   // 3200
            constexpr int SY = DZ;        // 16

            // density (accumulation order matches reference: 000..111)
            const float dens =
                vox[base]           * w000 + vox[base + 1]           * w001 +
                vox[base + SY]      * w010 + vox[base + SY + 1]      * w011 +
                vox[base + SX]      * w100 + vox[base + SX + 1]      * w101 +
                vox[base + SX + SY] * w110 + vox[base + SX + SY + 1] * w111;

            const float sig = valid ? (1.0f / (1.0f + __expf(-dens))) : 0.0f;

            const float newc = c + sig;
            // exactly 0 when saturated (min clamps) or invalid (sig==0)
            const float p = fminf(newc, 1.0f) - fminf(c, 1.0f);

            depth = fmaf(p, z, depth);

            #pragma unroll
            for (int ch = 0; ch < 3; ++ch) {
                const float* g = rgbg + ch * GRID_N;
                const float v =
                    g[base]           * w000 + g[base + 1]           * w001 +
                    g[base + SY]      * w010 + g[base + SY + 1]      * w011 +
                    g[base + SX]      * w100 + g[base + SX + 1]      * w101 +
                    g[base + SX + SY] * w110 + g[base + SX + SY + 1] * w111;
                if      (ch == 0) a0 = fmaf(p, v, a0);
                else if (ch == 1) a1 = fmaf(p, v, a1);
                else              a2 = fmaf(p, v, a2);
            }

            c = newc;
        }
        // wave-uniform early-out: every lane saturated or off the box
        if (__all((c >= 1.0f) || exited)) break;
    }

    // forced last sample for rays that left the bbox before saturating:
    // p_raw[last] = 1 outside, rgb zeroed outside => only depth gets the term.
    if (exited && (c < 1.0f)) depth = fmaf(1.0f - c, zlast, depth);

    out[r]             = depth;
    out[R + 3 * r]     = a0;
    out[R + 3 * r + 1] = a1;
    out[R + 3 * r + 2] = a2;
}

extern "C" void kernel_launch(void* const* d_in, const int* in_sizes, int n_in,
                              void* d_out, int out_size, void* d_ws, size_t ws_size,
                              hipStream_t stream) {
    const float* ro   = (const float*)d_in[0];
    const float* rd   = (const float*)d_in[1];
    const float* vox  = (const float*)d_in[2];
    const float* rgbg = (const float*)d_in[3];
    float* out = (float*)d_out;

    const int R = in_sizes[0] / 3;               // 86400
    const int block = 256;
    const int grid = (R + block - 1) / block;

    nerf_march_kernel<<<grid, block, 0, stream>>>(ro, rd, vox, rgbg, out, R);
}

// Round 3
// 72.571 us; speedup vs baseline: 1.0718x; 1.0718x over previous
//
#include <hip/hip_runtime.h>

// NeRFDecoderHead: ray-marched occupancy render. ALL I/O is float32.
//   inputs: rays_o (R,3), rays_d (R,3), voxel (1,200,200,16), rgb_recon (3,200,200,16)
//   output: depth (R) ++ rgb_marched (R,3), flat float32.
//
// v4 = revert to v1 (measured best, 71.8us). Experiment ledger:
//   v1 71.8us  per-sample early-break march                       [BEST]
//   v2 74.9us  AoS float4 repack: march unchanged -> NOT request-bound;
//              pack kernel pure +3.4us cost
//   v3 77.8us  predicated 4-sample chunks + wave-uniform break: march ~2x
//              slower -> rays saturate in ~2-3 samples, chunking does extra
//              work for saturated lanes; NOT latency-round-bound either
// Conclusion: timed window ~= 41us workspace poison fill (82% HBM peak,
// immovable) + ~25us harness reset dispatches + ~5us march. Keep v1's
// structure; only retain the division-free fmaf index math (VALU-neutral,
// carried through v2's unchanged march).
//
// Algorithmic notes:
//  * probs = diff(min(cumsum(p_raw),1)) with p_raw = inside ? sigmoid(dens) : 0,
//    and p_raw[last] = inside ? sig : 1.  Saturating scan => once running raw
//    sum c >= 1, all later probs are exactly 0 -> early break (~100x work cut).
//  * Ray origins are strictly inside the convex bbox, so the inside-set along
//    the ray is a prefix; at first outside sample only the forced last sample
//    remains: depth += (1-c)*z_last  (c < 1 invariant at that point).
//  * Trilinear weights computed once per sample, reused for density + 3 rgb
//    channels; accumulation order matches the reference (000..111).

namespace {
constexpr int DX = 200, DY = 200, DZ = 16;
constexpr int GRID_N = DX * DY * DZ;   // 640000 per channel
constexpr int NS = 287;                // N_SAMPLES
constexpr float ZSTEP = 0.2f;          // stepsize(0.5) * voxel_size(0.4)
} // namespace

extern "C" __global__ void __launch_bounds__(256)
nerf_march_kernel(const float* __restrict__ ro,
                  const float* __restrict__ rd,
                  const float* __restrict__ vox,
                  const float* __restrict__ rgbg,
                  float* __restrict__ out, int R)
{
    const int r = blockIdx.x * blockDim.x + threadIdx.x;
    if (r >= R) return;

    const float ox = ro[3 * r + 0];
    const float oy = ro[3 * r + 1];
    const float oz = ro[3 * r + 2];
    const float dx = rd[3 * r + 0];
    const float dy = rd[3 * r + 1];
    const float dz = rd[3 * r + 2];

    float c = 0.0f;                 // running (unclamped) cumsum of probs_raw
    float depth = 0.0f;
    float a0 = 0.0f, a1 = 0.0f, a2 = 0.0f;
    const float zlast = ZSTEP * (float)(NS - 1);   // 57.2

    #pragma unroll 1
    for (int n = 0; n < NS; ++n) {
        const float z  = ZSTEP * (float)n;
        const float px = fmaf(dx, z, ox);
        const float py = fmaf(dy, z, oy);
        const float pz = fmaf(dz, z, oz);

        const bool inside = (px >= -40.0f) & (px <= 40.0f) &
                            (py >= -40.0f) & (py <= 40.0f) &
                            (pz >= -1.0f)  & (pz <= 5.4f);
        if (!inside) {
            // prefix property: all remaining samples outside; only the forced
            // last sample (p_raw = 1) contributes, rgb zeroed outside.
            // loop invariant: c < 1 here (saturation breaks below).
            depth = fmaf(1.0f - c, zlast, depth);
            break;
        }

        // trilinear index/weights (align_corners=true: idx = u*(dim-1))
        // (px+40)/80*199 == px*2.4875 + 99.5 ; (pz+1)/6.4*15 == pz*2.34375 + 2.34375
        const float fx = fminf(fmaxf(fmaf(px, 2.4875f,  99.5f),    0.0f), 199.0f);
        const float fy = fminf(fmaxf(fmaf(py, 2.4875f,  99.5f),    0.0f), 199.0f);
        const float fz = fminf(fmaxf(fmaf(pz, 2.34375f, 2.34375f), 0.0f), 15.0f);
        const int ix = min((int)fx, DX - 2);   // fx >= 0 so cast == floor
        const int iy = min((int)fy, DY - 2);
        const int iz = min((int)fz, DZ - 2);
        const float wx = fx - (float)ix, wy = fy - (float)iy, wz = fz - (float)iz;
        const float ux = 1.0f - wx, uy = 1.0f - wy, uz = 1.0f - wz;

        const float w000 = ux * uy * uz, w001 = ux * uy * wz;
        const float w010 = ux * wy * uz, w011 = ux * wy * wz;
        const float w100 = wx * uy * uz, w101 = wx * uy * wz;
        const float w110 = wx * wy * uz, w111 = wx * wy * wz;

        const int base = (ix * DY + iy) * DZ + iz;
        constexpr int SX = DY * DZ;   // 3200
        constexpr int SY = DZ;        // 16

        // density sample (accumulation order matches reference: 000..111)
        const float dens =
            vox[base]           * w000 + vox[base + 1]           * w001 +
            vox[base + SY]      * w010 + vox[base + SY + 1]      * w011 +
            vox[base + SX]      * w100 + vox[base + SX + 1]      * w101 +
            vox[base + SX + SY] * w110 + vox[base + SX + SY + 1] * w111;

        const float sig = 1.0f / (1.0f + __expf(-dens));

        const float newc = c + sig;
        const float p = fminf(newc, 1.0f) - c;   // c < 1 invariant => min(c,1)==c

        depth = fmaf(p, z, depth);

        // rgb channels reuse the weights
        #pragma unroll
        for (int ch = 0; ch < 3; ++ch) {
            const float* g = rgbg + ch * GRID_N;
            const float v =
                g[base]           * w000 + g[base + 1]           * w001 +
                g[base + SY]      * w010 + g[base + SY + 1]      * w011 +
                g[base + SX]      * w100 + g[base + SX + 1]      * w101 +
                g[base + SX + SY] * w110 + g[base + SX + SY + 1] * w111;
            if      (ch == 0) a0 = fmaf(p, v, a0);
            else if (ch == 1) a1 = fmaf(p, v, a1);
            else              a2 = fmaf(p, v, a2);
        }

        c = newc;
        if (c >= 1.0f) break;   // saturated: every later probs[n] == 0
    }

    out[r]             = depth;
    out[R + 3 * r]     = a0;
    out[R + 3 * r + 1] = a1;
    out[R + 3 * r + 2] = a2;
}

extern "C" void kernel_launch(void* const* d_in, const int* in_sizes, int n_in,
                              void* d_out, int out_size, void* d_ws, size_t ws_size,
                              hipStream_t stream) {
    const float* ro   = (const float*)d_in[0];
    const float* rd   = (const float*)d_in[1];
    const float* vox  = (const float*)d_in[2];
    const float* rgbg = (const float*)d_in[3];
    float* out = (float*)d_out;

    const int R = in_sizes[0] / 3;               // 86400
    const int block = 256;
    const int grid = (R + block - 1) / block;

    nerf_march_kernel<<<grid, block, 0, stream>>>(ro, rd, vox, rgbg, out, R);
}